// Round 12
// baseline (311.203 us; speedup 1.0000x reference)
//
#include <hip/hip_runtime.h>
#include <hip/hip_bf16.h>

#define N_USERS 100000
#define N_ITEMS 50000
#define N_NODES 150000
#define DIM 64
#define N_EDGES 4000000
#define BATCH 4096

#define NBKT 256
#define BW 588           // nodes per bucket; 256*588 = 150528 >= 150000
#define STRIDE 16640     // tmp records per bucket (mean 15680, sigma ~124 -> +7.7 sigma)
#define PA_EDGES 4096    // edges per partition block
#define PA_ITER 16       // edges per thread (register-cached)
#define PA_BLOCKS ((N_EDGES + PA_EDGES - 1) / PA_EDGES)   // 977 (<= 1024 slots at 4/CU: ONE generation)
#define CVT_THREADS (N_NODES * DIM / 8)                   // 1,200,000 (exact: DIM%8==0)
#define CVT_BLOCKS 512                                    // grid-stride convert blocks
#define BS_ITER 32       // bsort records per thread; 32*512=16384 >= realized bucket max (~16016)

// ---------------- bf16 helpers ----------------
__device__ __forceinline__ float blo(unsigned int u) { return __uint_as_float(u << 16); }
__device__ __forceinline__ float bhi(unsigned int u) { return __uint_as_float(u & 0xffff0000u); }
__device__ __forceinline__ unsigned int f2b(float f) {  // RTNE
    unsigned int x = __float_as_uint(f);
    return (x + 0x7fffu + ((x >> 16) & 1u)) >> 16;
}
__device__ __forceinline__ unsigned int pack2(float a, float b) {
    return f2b(a) | (f2b(b) << 16);
}

typedef float v2f __attribute__((ext_vector_type(2)));

// ---------------- pure two-pass register-cached partition ----------------
// R12: NBKT 512->256. LDS 46->39 KB => 4 blocks/CU => 977 blocks run in ONE generation
// (was 3/CU, 2 generations with a 209-block straggler tail). Per-(block,bin) runs double
// to ~16 records = 128 B full lines. Reserve order rotated per block to decorrelate the
// gcur atomic storm (was: all 977 blocks hammering gcur[0..255] in identical order).
__global__ void __launch_bounds__(256, 4) k_partition(
        const int* __restrict__ src, const int* __restrict__ dst,
        const float* __restrict__ vals,
        int* __restrict__ gcur, int2* __restrict__ tmp) {
    __shared__ int cnt[NBKT];       // pass-1 histogram, then reused as pass-2 cursor
    __shared__ int base_s[NBKT];    // reserved global run base per bin
    __shared__ int off_s[NBKT];     // block-local exclusive scan of cnt
    __shared__ int2 rec_s[PA_EDGES];          // 32 KB bin-sorted records
    __shared__ unsigned char bin_s[PA_EDGES]; // 4 KB bin tag per sorted slot (256 bins -> uchar)
    int t = threadIdx.x;
    int myb[PA_ITER];    // load: raw dst; process: bin (or -1)
    int mykey[PA_ITER];  // load: raw src; process: (s<<10)|local
    int myval[PA_ITER];  // raw value bits
    size_t base = (size_t)blockIdx.x * PA_EDGES;
    // batched load phase: all loads issue back-to-back, no dependent use in between (R6 win)
#pragma unroll
    for (int it = 0; it < PA_ITER; it++) {
        size_t i = base + (size_t)it * 256 + t;
        if (i < N_EDGES) {
            myb[it] = __builtin_nontemporal_load(dst + i);
            mykey[it] = __builtin_nontemporal_load(src + i);
            myval[it] = __float_as_int(__builtin_nontemporal_load(vals + i));
        } else {
            myb[it] = -1;
        }
    }
    for (int i = t; i < NBKT; i += 256) cnt[i] = 0;
    __syncthreads();
    // process phase: convert in place + histogram
#pragma unroll
    for (int it = 0; it < PA_ITER; it++) {
        int d = myb[it];
        if (d >= 0) {
            int b = d / BW;
            mykey[it] = (mykey[it] << 10) | (d - b * BW);
            myb[it] = b;
            atomicAdd(&cnt[b], 1);
        }
    }
    __syncthreads();
    // reserve global runs, block-rotated bin order (decorrelates cross-block contention)
    {
        int bb = (t + blockIdx.x * 37) & (NBKT - 1);
        int c = cnt[bb];
        base_s[bb] = (c > 0) ? atomicAdd(&gcur[bb], c) : 0;
    }
    // block-local exclusive scan of cnt -> off_s (single wave, 4 chunks of 64)
    if (t < 64) {
        int lane = t;
        int carry = 0;
        for (int c = 0; c < NBKT / 64; c++) {
            int i = c * 64 + lane;
            int x = cnt[i];
            int incl = x;
            for (int o = 1; o < 64; o <<= 1) {
                int y = __shfl_up(incl, o);
                if (lane >= o) incl += y;
            }
            off_s[i] = carry + incl - x;
            carry += __shfl(incl, 63);
        }
    }
    __syncthreads();
    for (int i = t; i < NBKT; i += 256) cnt[i] = 0;  // reuse as cursor
    __syncthreads();
    // pass 2a: scatter from registers into bin-sorted LDS slots
#pragma unroll
    for (int it = 0; it < PA_ITER; it++) {
        int b = myb[it];
        if (b >= 0) {
            int pos = off_s[b] + atomicAdd(&cnt[b], 1);
            rec_s[pos] = make_int2(mykey[it], myval[it]);
            bin_s[pos] = (unsigned char)b;
        }
    }
    __syncthreads();
    // pass 2b: linear readout -> coalesced global runs (~128 B full lines per bin)
    int nrec = off_s[NBKT - 1] + cnt[NBKT - 1];
    for (int i = t; i < nrec; i += 256) {
        int2 r = rec_s[i];
        int b = bin_s[i];
        tmp[(size_t)b * STRIDE + base_s[b] + (i - off_s[b])] = r;
    }
}

// ---------------- pass B: sort within bucket + table convert (fused grid) ----------------
// blocks [0, NBKT): LDS-staged bucket sort -> dense CSR. One bucket = ~15.7K records in
// 133 KB dynamic LDS -> 1 block/CU, 256 blocks = one generation. blocks [NBKT, NBKT+512):
// grid-stride fp32->bf16 table convert (ebf0 first needed by spmm-1, after this kernel).
__global__ void k_bsortcvt(const int2* __restrict__ tmp, const int* __restrict__ gcur,
                           int* __restrict__ row_ptr, int2* __restrict__ fin,
                           const float* __restrict__ uemb, const float* __restrict__ iemb,
                           ushort* __restrict__ ebf0) {
    __shared__ int cnt[BW + 64];
    __shared__ int off[BW + 64];
    __shared__ int gbase_s;
    extern __shared__ int2 rec2[];  // STRIDE slots, node-sorted final records
    int b = blockIdx.x, t = threadIdx.x;  // 512 threads
    if (b >= NBKT) {
        // ---- convert branch: grid-stride, 8 floats/iteration, fully coalesced ----
        for (int idx = (b - NBKT) * 512 + t; idx < CVT_THREADS; idx += CVT_BLOCKS * 512) {
            int i = idx * 8;
            const float* srcp = (i < N_USERS * DIM) ? (uemb + i) : (iemb + (i - N_USERS * DIM));
            float4 v0, v1;
            v0.x = __builtin_nontemporal_load(srcp + 0);
            v0.y = __builtin_nontemporal_load(srcp + 1);
            v0.z = __builtin_nontemporal_load(srcp + 2);
            v0.w = __builtin_nontemporal_load(srcp + 3);
            v1.x = __builtin_nontemporal_load(srcp + 4);
            v1.y = __builtin_nontemporal_load(srcp + 5);
            v1.z = __builtin_nontemporal_load(srcp + 6);
            v1.w = __builtin_nontemporal_load(srcp + 7);
            uint4 p;
            p.x = pack2(v0.x, v0.y);
            p.y = pack2(v0.z, v0.w);
            p.z = pack2(v1.x, v1.y);
            p.w = pack2(v1.z, v1.w);
            *(uint4*)(ebf0 + i) = p;
        }
        return;
    }
    // ---- bucket-sort branch ----
    int node0 = b * BW;
    int nodes = min(BW, N_NODES - node0);  // last bucket covers only 60 real nodes
    int count = gcur[b];
    const int2* tb = tmp + (size_t)b * STRIDE;
    // batched record load (sentinel .x=-1; real keys are >= 0)
    int2 myrec[BS_ITER];
#pragma unroll
    for (int it = 0; it < BS_ITER; it++) {
        int e = it * 512 + t;
        myrec[it] = (e < count) ? tb[e] : make_int2(-1, 0);
    }
    if (t < 64) {
        int ssum = 0;
#pragma unroll
        for (int j = 0; j < NBKT / 64; j++) {
            int idx = t * (NBKT / 64) + j;
            if (idx < b) ssum += gcur[idx];
        }
        for (int o = 32; o; o >>= 1) ssum += __shfl_xor(ssum, o);
        if (t == 0) gbase_s = ssum;
    }
    for (int i = t; i < BW + 64; i += 512) cnt[i] = 0;
    __syncthreads();
    int gbase = gbase_s;
#pragma unroll
    for (int it = 0; it < BS_ITER; it++)
        if (myrec[it].x >= 0) atomicAdd(&cnt[myrec[it].x & 1023], 1);
    for (int e = BS_ITER * 512 + t; e < count; e += 512)  // rare tail (count > 16384)
        atomicAdd(&cnt[tb[e].x & 1023], 1);
    __syncthreads();
    if (t < 64) {
        int lane = t;
        int carry = 0;
        for (int c = 0; c < 10; c++) {  // 10*64 = 640 >= BW+1
            int i = c * 64 + lane;
            int x = (i < nodes) ? cnt[i] : 0;
            int incl = x;
            for (int o = 1; o < 64; o <<= 1) {
                int y = __shfl_up(incl, o);
                if (lane >= o) incl += y;
            }
            if (i <= nodes) off[i] = carry + incl - x;
            carry += __shfl(incl, 63);
        }
    }
    __syncthreads();
    for (int i = t; i <= nodes; i += 512)
        if (node0 + i <= N_NODES) row_ptr[node0 + i] = gbase + off[i];
    __syncthreads();
    // scatter into node-sorted LDS (store final record form)
#pragma unroll
    for (int it = 0; it < BS_ITER; it++) {
        int2 r = myrec[it];
        if (r.x >= 0) {
            int pos = atomicAdd(&off[r.x & 1023], 1);
            rec2[pos] = make_int2(r.x >> 10, r.y);
        }
    }
    for (int e = BS_ITER * 512 + t; e < count; e += 512) {  // rare tail
        int2 r = tb[e];
        int pos = atomicAdd(&off[r.x & 1023], 1);
        rec2[pos] = make_int2(r.x >> 10, r.y);
    }
    __syncthreads();
    // linear readout -> fully coalesced fin writes
    for (int i = t; i < count; i += 512) fin[gbase + i] = rec2[i];
}

// ---------------- bf16 SpMM: one wave per dst node, 8 groups x 8 lanes ----------------
// R7 proven-best form (67.2 us): PLAIN fin loads / PLAIN eout store (NT refuted R9).
// Single fully-predicated 32-edge burst, 4 gathers in flight per wave (MLP probes R1-R5
// bracket this as the fabric plateau ~3.7 TB/s).

// one edge record: gather 16B of the src row, packed-FMA into 4x float2 accumulators
#define EDGE_FMA(r, u, A0, A1, A2, A3)                                        \
    {                                                                         \
        float vf = __int_as_float((r).y);                                     \
        v2f vv = {vf, vf};                                                    \
        v2f f0 = {blo((u).x), bhi((u).x)};                                    \
        v2f f1 = {blo((u).y), bhi((u).y)};                                    \
        v2f f2 = {blo((u).z), bhi((u).z)};                                    \
        v2f f3 = {blo((u).w), bhi((u).w)};                                    \
        A0 = __builtin_elementwise_fma(vv, f0, A0);                           \
        A1 = __builtin_elementwise_fma(vv, f1, A1);                           \
        A2 = __builtin_elementwise_fma(vv, f2, A2);                           \
        A3 = __builtin_elementwise_fma(vv, f3, A3);                           \
    }

// 32-bit byte offsets: table is 19.2 MB, record arrays <= 34 MB -> SADDR + voffset form
#define GATHER16(basec, r) (*(const uint4*)((basec) + ((((unsigned int)(r).x) << 7) | qoff)))
#define REC8(basec, i) (*(const int2*)((basec) + (((unsigned int)(i)) << 3)))

// clamped 32-edge burst: all 4 rec loads + all 4 gathers issue before any FMA waits
#define BURST32(basec, e, end, last, X0, X1, X2, X3)                          \
    {                                                                         \
        int e1 = (e) + 8, e2 = (e) + 16, e3 = (e) + 24;                       \
        int2 ra = REC8(basec, (e));                                           \
        int2 rb = REC8(basec, min(e1, last));                                 \
        int2 rc = REC8(basec, min(e2, last));                                 \
        int2 rd = REC8(basec, min(e3, last));                                 \
        rb.y = (e1 < (end)) ? rb.y : 0;                                       \
        rc.y = (e2 < (end)) ? rc.y : 0;                                       \
        rd.y = (e3 < (end)) ? rd.y : 0;                                       \
        uint4 ua = GATHER16(einc, ra);                                        \
        uint4 ub = GATHER16(einc, rb);                                        \
        uint4 uc = GATHER16(einc, rc);                                        \
        uint4 ud = GATHER16(einc, rd);                                        \
        EDGE_FMA(ra, ua, X0, X1, X2, X3);                                     \
        EDGE_FMA(rb, ub, X0, X1, X2, X3);                                     \
        EDGE_FMA(rc, uc, X0, X1, X2, X3);                                     \
        EDGE_FMA(rd, ud, X0, X1, X2, X3);                                     \
        (e) += 32;                                                            \
    }

__global__ void k_spmm16(const ushort* __restrict__ ein, ushort* __restrict__ eout,
                         const int* __restrict__ row_ptr, const int2* __restrict__ fin) {
    int wave = (blockIdx.x * blockDim.x + threadIdx.x) >> 6;
    if (wave >= N_NODES) return;
    int lane = threadIdx.x & 63;
    int g = lane >> 3;  // edge group 0..7
    int q = lane & 7;   // 8 bf16 dims per lane
    unsigned int qoff = (unsigned int)q << 4;
    const char* einc = (const char*)ein;
    const char* finc = (const char*)fin;
    int start = row_ptr[wave], end = row_ptr[wave + 1];
    int last = max(start, end - 1);  // safe clamp target (>=0 even for empty head rows)
    v2f A0 = {0.f, 0.f}, A1 = {0.f, 0.f}, A2 = {0.f, 0.f}, A3 = {0.f, 0.f};
    int e = start + g;
    // deg <= 32 (87% of nodes): exactly one burst; rare high-degree nodes loop
    while (e < end) BURST32(finc, e, end, last, A0, A1, A2, A3);
#pragma unroll
    for (int off = 8; off < 64; off <<= 1) {
        A0.x += __shfl_xor(A0.x, off);
        A0.y += __shfl_xor(A0.y, off);
        A1.x += __shfl_xor(A1.x, off);
        A1.y += __shfl_xor(A1.y, off);
        A2.x += __shfl_xor(A2.x, off);
        A2.y += __shfl_xor(A2.y, off);
        A3.x += __shfl_xor(A3.x, off);
        A3.y += __shfl_xor(A3.y, off);
    }
    if (lane < 8) {
        uint4 p;
        p.x = pack2(A0.x, A0.y);
        p.y = pack2(A1.x, A1.y);
        p.z = pack2(A2.x, A2.y);
        p.w = pack2(A3.x, A3.y);
        *(uint4*)(eout + (size_t)wave * DIM + q * 8) = p;
    }
}

// ---------------- fused sampled tail: layer-3 + layer accumulate + dot ----------------
// One wave per (user,item) pair; layer-3 from the dense CSR over ebf2, layers 0..2 as
// direct row reads, per-lane dot + 3-step xor reduce.
__global__ void k_sampdot(const float* __restrict__ uemb, const float* __restrict__ iemb,
                          const ushort* __restrict__ ebf1, const ushort* __restrict__ ebf2,
                          const int* __restrict__ row_ptr, const int2* __restrict__ fin,
                          const int* __restrict__ users, const int* __restrict__ items,
                          float* __restrict__ out) {
    int b = (blockIdx.x * blockDim.x + threadIdx.x) >> 6;
    if (b >= BATCH) return;
    int lane = threadIdx.x & 63;
    int g = lane >> 3;
    int q = lane & 7;
    unsigned int qoff = (unsigned int)q << 4;
    const char* einc = (const char*)ebf2;  // layer-3 propagates from ebf2
    const char* finc = (const char*)fin;
    int iu = users[b];
    int ii = items[b];
    int nu = iu, ni = ii + N_USERS;
    // ---- user row ----
    v2f A0 = {0.f, 0.f}, A1 = {0.f, 0.f}, A2 = {0.f, 0.f}, A3 = {0.f, 0.f};
    {
        int start = row_ptr[nu], end = row_ptr[nu + 1];
        int last = max(start, end - 1);
        int e = start + g;
        while (e < end) BURST32(finc, e, end, last, A0, A1, A2, A3);
    }
    // ---- item row ----
    v2f B0 = {0.f, 0.f}, B1 = {0.f, 0.f}, B2 = {0.f, 0.f}, B3 = {0.f, 0.f};
    {
        int start = row_ptr[ni], end = row_ptr[ni + 1];
        int last = max(start, end - 1);
        int e = start + g;
        while (e < end) BURST32(finc, e, end, last, B0, B1, B2, B3);
    }
#pragma unroll
    for (int off = 8; off < 64; off <<= 1) {
        A0.x += __shfl_xor(A0.x, off);
        A0.y += __shfl_xor(A0.y, off);
        A1.x += __shfl_xor(A1.x, off);
        A1.y += __shfl_xor(A1.y, off);
        A2.x += __shfl_xor(A2.x, off);
        A2.y += __shfl_xor(A2.y, off);
        A3.x += __shfl_xor(A3.x, off);
        A3.y += __shfl_xor(A3.y, off);
        B0.x += __shfl_xor(B0.x, off);
        B0.y += __shfl_xor(B0.y, off);
        B1.x += __shfl_xor(B1.x, off);
        B1.y += __shfl_xor(B1.y, off);
        B2.x += __shfl_xor(B2.x, off);
        B2.y += __shfl_xor(B2.y, off);
        B3.x += __shfl_xor(B3.x, off);
        B3.y += __shfl_xor(B3.y, off);
    }
    // layers 0..2: fp32 table row + ebf1 row + ebf2 row (each lane: dims q*8..q*8+7)
    {
        const float4* fp = (const float4*)(uemb + (size_t)nu * DIM + q * 8);
        float4 fa = fp[0], fb = fp[1];
        uint4 u1 = *(const uint4*)(ebf1 + (size_t)nu * DIM + q * 8);
        uint4 u2 = *(const uint4*)(ebf2 + (size_t)nu * DIM + q * 8);
        A0.x += fa.x + blo(u1.x) + blo(u2.x); A0.y += fa.y + bhi(u1.x) + bhi(u2.x);
        A1.x += fa.z + blo(u1.y) + blo(u2.y); A1.y += fa.w + bhi(u1.y) + bhi(u2.y);
        A2.x += fb.x + blo(u1.z) + blo(u2.z); A2.y += fb.y + bhi(u1.z) + bhi(u2.z);
        A3.x += fb.z + blo(u1.w) + blo(u2.w); A3.y += fb.w + bhi(u1.w) + bhi(u2.w);
    }
    {
        const float4* fp = (const float4*)(iemb + (size_t)ii * DIM + q * 8);
        float4 fa = fp[0], fb = fp[1];
        uint4 u1 = *(const uint4*)(ebf1 + (size_t)ni * DIM + q * 8);
        uint4 u2 = *(const uint4*)(ebf2 + (size_t)ni * DIM + q * 8);
        B0.x += fa.x + blo(u1.x) + blo(u2.x); B0.y += fa.y + bhi(u1.x) + bhi(u2.x);
        B1.x += fa.z + blo(u1.y) + blo(u2.y); B1.y += fa.w + bhi(u1.y) + bhi(u2.y);
        B2.x += fb.x + blo(u1.z) + blo(u2.z); B2.y += fb.y + bhi(u1.z) + bhi(u2.z);
        B3.x += fb.z + blo(u1.w) + blo(u2.w); B3.y += fb.w + bhi(u1.w) + bhi(u2.w);
    }
    // dot: per-lane 8-dim product, reduce across q (lanes 0..7 cover all 64 dims)
    float p = A0.x * B0.x + A0.y * B0.y + A1.x * B1.x + A1.y * B1.y +
              A2.x * B2.x + A2.y * B2.y + A3.x * B3.x + A3.y * B3.y;
    p += __shfl_xor(p, 1);
    p += __shfl_xor(p, 2);
    p += __shfl_xor(p, 4);
    if (lane == 0) out[b] = p * (1.0f / 16.0f);  // (acc/4)·(acc/4)
}

// ---------------- launch ----------------

extern "C" void kernel_launch(void* const* d_in, const int* in_sizes, int n_in,
                              void* d_out, int out_size, void* d_ws, size_t ws_size,
                              hipStream_t stream) {
    const float* user_emb = (const float*)d_in[0];
    const float* item_emb = (const float*)d_in[1];
    const float* vals = (const float*)d_in[2];
    const int* src = (const int*)d_in[3];
    const int* dst = (const int*)d_in[4];
    const int* users = (const int*)d_in[5];
    const int* items = (const int*)d_in[6];
    float* out = (float*)d_out;

    char* ws = (char*)d_ws;
    size_t off = 0;
    auto alloc = [&](size_t bytes) {
        char* p = ws + off;
        off += (bytes + 255) & ~(size_t)255;
        return p;
    };
    ushort* ebf0 = (ushort*)alloc((size_t)N_NODES * DIM * 2);  // 19.2 MB bf16 concat tables
    ushort* ebf1 = (ushort*)alloc((size_t)N_NODES * DIM * 2);  // layer-1 out (aliases tmp lo)
    ushort* ebf2 = (ushort*)alloc((size_t)N_NODES * DIM * 2);  // layer-2 out (aliases tmp hi)
    int2* fin = (int2*)alloc((size_t)N_EDGES * 8);             // 32 MB dense CSR records
    int* row_ptr = (int*)alloc((size_t)(N_NODES + 1) * 4);
    int* gcur = (int*)alloc((size_t)NBKT * 4);
    // 34.1 MB fixed-stride partition scratch aliases ebf1+ebf2 (38.4 MB contiguous);
    // tmp is dead after k_bsortcvt, before ebf1/2 are first written.
    int2* tmp = (int2*)ebf1;

    (void)hipMemsetAsync(gcur, 0, (size_t)NBKT * 4, stream);

    // pure partition (977 blocks, one generation at 4 blocks/CU)
    k_partition<<<PA_BLOCKS, 256, 0, stream>>>(src, dst, vals, gcur, tmp);
    // bucket sort (256 blocks, 133 KB dyn LDS, one generation) + grid-stride convert
    k_bsortcvt<<<NBKT + CVT_BLOCKS, 512, (size_t)STRIDE * 8, stream>>>(
        tmp, gcur, row_ptr, fin, user_emb, item_emb, ebf0);

    int spmm_blocks = (N_NODES * 64 + 255) / 256;  // one wave per node
    // layer 1: ebf0 -> ebf1; layer 2: ebf1 -> ebf2
    k_spmm16<<<spmm_blocks, 256, 0, stream>>>(ebf0, ebf1, row_ptr, fin);
    k_spmm16<<<spmm_blocks, 256, 0, stream>>>(ebf1, ebf2, row_ptr, fin);
    // fused sampled tail: layer-3 + layer-0/1/2 accumulate + dot
    k_sampdot<<<(BATCH * 64 + 255) / 256, 256, 0, stream>>>(
        user_emb, item_emb, ebf1, ebf2, row_ptr, fin, users, items, out);
}

// Round 13
// 305.935 us; speedup vs baseline: 1.0172x; 1.0172x over previous
//
#include <hip/hip_runtime.h>
#include <hip/hip_bf16.h>

#define N_USERS 100000
#define N_ITEMS 50000
#define N_NODES 150000
#define DIM 64
#define N_EDGES 4000000
#define BATCH 4096

#define NBKT 256
#define BW 588           // nodes per bucket; 256*588 = 150528 >= 150000
#define STRIDE 16640     // tmp records per bucket (mean 15680, sigma ~124 -> +7.7 sigma)
#define PA_EDGES 4096    // edges per partition block
#define PA_ITER 16       // edges per thread (register-cached)
#define PA_BLOCKS ((N_EDGES + PA_EDGES - 1) / PA_EDGES)   // 977
#define CVT_THREADS (N_NODES * DIM / 8)                   // 1,200,000 (exact: DIM%8==0)
#define CVT_BLOCKS 512                                    // grid-stride convert blocks
#define BS_ITER 32       // bsort records per thread; 32*512=16384 >= realized bucket max
#define SPMM_BLOCKS ((N_NODES * 64 + 255) / 256)          // 37500
#define MARK_BLOCKS 32                                    // 32*256 = 8192 = 2*BATCH marker threads
#define BMAP_WORDS ((N_NODES + 31) / 32)                  // 4688 words = 18.75 KB

// ---------------- bf16 helpers ----------------
__device__ __forceinline__ float blo(unsigned int u) { return __uint_as_float(u << 16); }
__device__ __forceinline__ float bhi(unsigned int u) { return __uint_as_float(u & 0xffff0000u); }
__device__ __forceinline__ unsigned int f2b(float f) {  // RTNE
    unsigned int x = __float_as_uint(f);
    return (x + 0x7fffu + ((x >> 16) & 1u)) >> 16;
}
__device__ __forceinline__ unsigned int pack2(float a, float b) {
    return f2b(a) | (f2b(b) << 16);
}

typedef float v2f __attribute__((ext_vector_type(2)));

// ---------------- pure two-pass register-cached partition ----------------
// batched load phase (R6 win), LDS-sorted writeout (R3 win). NBKT=256 form (R12,
// measured == NBKT=512 within noise).
__global__ void __launch_bounds__(256, 4) k_partition(
        const int* __restrict__ src, const int* __restrict__ dst,
        const float* __restrict__ vals,
        int* __restrict__ gcur, int2* __restrict__ tmp) {
    __shared__ int cnt[NBKT];       // pass-1 histogram, then reused as pass-2 cursor
    __shared__ int base_s[NBKT];    // reserved global run base per bin
    __shared__ int off_s[NBKT];     // block-local exclusive scan of cnt
    __shared__ int2 rec_s[PA_EDGES];          // 32 KB bin-sorted records
    __shared__ unsigned char bin_s[PA_EDGES]; // 4 KB bin tag per sorted slot
    int t = threadIdx.x;
    int myb[PA_ITER];    // load: raw dst; process: bin (or -1)
    int mykey[PA_ITER];  // load: raw src; process: (s<<10)|local
    int myval[PA_ITER];  // raw value bits
    size_t base = (size_t)blockIdx.x * PA_EDGES;
    // batched load phase: all loads issue back-to-back, no dependent use in between
#pragma unroll
    for (int it = 0; it < PA_ITER; it++) {
        size_t i = base + (size_t)it * 256 + t;
        if (i < N_EDGES) {
            myb[it] = __builtin_nontemporal_load(dst + i);
            mykey[it] = __builtin_nontemporal_load(src + i);
            myval[it] = __float_as_int(__builtin_nontemporal_load(vals + i));
        } else {
            myb[it] = -1;
        }
    }
    for (int i = t; i < NBKT; i += 256) cnt[i] = 0;
    __syncthreads();
    // process phase: convert in place + histogram
#pragma unroll
    for (int it = 0; it < PA_ITER; it++) {
        int d = myb[it];
        if (d >= 0) {
            int b = d / BW;
            mykey[it] = (mykey[it] << 10) | (d - b * BW);
            myb[it] = b;
            atomicAdd(&cnt[b], 1);
        }
    }
    __syncthreads();
    // reserve global runs, block-rotated bin order
    {
        int bb = (t + blockIdx.x * 37) & (NBKT - 1);
        int c = cnt[bb];
        base_s[bb] = (c > 0) ? atomicAdd(&gcur[bb], c) : 0;
    }
    // block-local exclusive scan of cnt -> off_s (single wave, 4 chunks of 64)
    if (t < 64) {
        int lane = t;
        int carry = 0;
        for (int c = 0; c < NBKT / 64; c++) {
            int i = c * 64 + lane;
            int x = cnt[i];
            int incl = x;
            for (int o = 1; o < 64; o <<= 1) {
                int y = __shfl_up(incl, o);
                if (lane >= o) incl += y;
            }
            off_s[i] = carry + incl - x;
            carry += __shfl(incl, 63);
        }
    }
    __syncthreads();
    for (int i = t; i < NBKT; i += 256) cnt[i] = 0;  // reuse as cursor
    __syncthreads();
    // pass 2a: scatter from registers into bin-sorted LDS slots
#pragma unroll
    for (int it = 0; it < PA_ITER; it++) {
        int b = myb[it];
        if (b >= 0) {
            int pos = off_s[b] + atomicAdd(&cnt[b], 1);
            rec_s[pos] = make_int2(mykey[it], myval[it]);
            bin_s[pos] = (unsigned char)b;
        }
    }
    __syncthreads();
    // pass 2b: linear readout -> coalesced global runs
    int nrec = off_s[NBKT - 1] + cnt[NBKT - 1];
    for (int i = t; i < nrec; i += 256) {
        int2 r = rec_s[i];
        int b = bin_s[i];
        tmp[(size_t)b * STRIDE + base_s[b] + (i - off_s[b])] = r;
    }
}

// ---------------- pass B: sort within bucket + table convert (fused grid) ----------------
__global__ void k_bsortcvt(const int2* __restrict__ tmp, const int* __restrict__ gcur,
                           int* __restrict__ row_ptr, int2* __restrict__ fin,
                           const float* __restrict__ uemb, const float* __restrict__ iemb,
                           ushort* __restrict__ ebf0) {
    __shared__ int cnt[BW + 64];
    __shared__ int off[BW + 64];
    __shared__ int gbase_s;
    extern __shared__ int2 rec2[];  // STRIDE slots, node-sorted final records
    int b = blockIdx.x, t = threadIdx.x;  // 512 threads
    if (b >= NBKT) {
        // ---- convert branch: grid-stride, 8 floats/iteration, fully coalesced ----
        for (int idx = (b - NBKT) * 512 + t; idx < CVT_THREADS; idx += CVT_BLOCKS * 512) {
            int i = idx * 8;
            const float* srcp = (i < N_USERS * DIM) ? (uemb + i) : (iemb + (i - N_USERS * DIM));
            float4 v0, v1;
            v0.x = __builtin_nontemporal_load(srcp + 0);
            v0.y = __builtin_nontemporal_load(srcp + 1);
            v0.z = __builtin_nontemporal_load(srcp + 2);
            v0.w = __builtin_nontemporal_load(srcp + 3);
            v1.x = __builtin_nontemporal_load(srcp + 4);
            v1.y = __builtin_nontemporal_load(srcp + 5);
            v1.z = __builtin_nontemporal_load(srcp + 6);
            v1.w = __builtin_nontemporal_load(srcp + 7);
            uint4 p;
            p.x = pack2(v0.x, v0.y);
            p.y = pack2(v0.z, v0.w);
            p.z = pack2(v1.x, v1.y);
            p.w = pack2(v1.z, v1.w);
            *(uint4*)(ebf0 + i) = p;
        }
        return;
    }
    // ---- bucket-sort branch ----
    int node0 = b * BW;
    int nodes = min(BW, N_NODES - node0);
    int count = gcur[b];
    const int2* tb = tmp + (size_t)b * STRIDE;
    // batched record load (sentinel .x=-1; real keys are >= 0)
    int2 myrec[BS_ITER];
#pragma unroll
    for (int it = 0; it < BS_ITER; it++) {
        int e = it * 512 + t;
        myrec[it] = (e < count) ? tb[e] : make_int2(-1, 0);
    }
    if (t < 64) {
        int ssum = 0;
#pragma unroll
        for (int j = 0; j < NBKT / 64; j++) {
            int idx = t * (NBKT / 64) + j;
            if (idx < b) ssum += gcur[idx];
        }
        for (int o = 32; o; o >>= 1) ssum += __shfl_xor(ssum, o);
        if (t == 0) gbase_s = ssum;
    }
    for (int i = t; i < BW + 64; i += 512) cnt[i] = 0;
    __syncthreads();
    int gbase = gbase_s;
#pragma unroll
    for (int it = 0; it < BS_ITER; it++)
        if (myrec[it].x >= 0) atomicAdd(&cnt[myrec[it].x & 1023], 1);
    for (int e = BS_ITER * 512 + t; e < count; e += 512)
        atomicAdd(&cnt[tb[e].x & 1023], 1);
    __syncthreads();
    if (t < 64) {
        int lane = t;
        int carry = 0;
        for (int c = 0; c < 10; c++) {  // 10*64 = 640 >= BW+1
            int i = c * 64 + lane;
            int x = (i < nodes) ? cnt[i] : 0;
            int incl = x;
            for (int o = 1; o < 64; o <<= 1) {
                int y = __shfl_up(incl, o);
                if (lane >= o) incl += y;
            }
            if (i <= nodes) off[i] = carry + incl - x;
            carry += __shfl(incl, 63);
        }
    }
    __syncthreads();
    for (int i = t; i <= nodes; i += 512)
        if (node0 + i <= N_NODES) row_ptr[node0 + i] = gbase + off[i];
    __syncthreads();
    // scatter into node-sorted LDS (store final record form)
#pragma unroll
    for (int it = 0; it < BS_ITER; it++) {
        int2 r = myrec[it];
        if (r.x >= 0) {
            int pos = atomicAdd(&off[r.x & 1023], 1);
            rec2[pos] = make_int2(r.x >> 10, r.y);
        }
    }
    for (int e = BS_ITER * 512 + t; e < count; e += 512) {
        int2 r = tb[e];
        int pos = atomicAdd(&off[r.x & 1023], 1);
        rec2[pos] = make_int2(r.x >> 10, r.y);
    }
    __syncthreads();
    // linear readout -> fully coalesced fin writes
    for (int i = t; i < count; i += 512) fin[gbase + i] = rec2[i];
}

// ---------------- bf16 SpMM: one wave per dst node, 8 groups x 8 lanes ----------------
// R7 proven-best inner form (67.2 us). R13: pass-2 computes only MARKED rows (ebf2 is
// consumed solely at sampled nodes + their in-edge srcs = ~77% of nodes); pass-1 carries
// 32 marker blocks at the grid front that build the bitmap (needed only by pass 2).

// one edge record: gather 16B of the src row, packed-FMA into 4x float2 accumulators
#define EDGE_FMA(r, u, A0, A1, A2, A3)                                        \
    {                                                                         \
        float vf = __int_as_float((r).y);                                     \
        v2f vv = {vf, vf};                                                    \
        v2f f0 = {blo((u).x), bhi((u).x)};                                    \
        v2f f1 = {blo((u).y), bhi((u).y)};                                    \
        v2f f2 = {blo((u).z), bhi((u).z)};                                    \
        v2f f3 = {blo((u).w), bhi((u).w)};                                    \
        A0 = __builtin_elementwise_fma(vv, f0, A0);                           \
        A1 = __builtin_elementwise_fma(vv, f1, A1);                           \
        A2 = __builtin_elementwise_fma(vv, f2, A2);                           \
        A3 = __builtin_elementwise_fma(vv, f3, A3);                           \
    }

// 32-bit byte offsets: table is 19.2 MB, record arrays <= 34 MB -> SADDR + voffset form
#define GATHER16(basec, r) (*(const uint4*)((basec) + ((((unsigned int)(r).x) << 7) | qoff)))
#define REC8(basec, i) (*(const int2*)((basec) + (((unsigned int)(i)) << 3)))

// clamped 32-edge burst: all 4 rec loads + all 4 gathers issue before any FMA waits
#define BURST32(basec, e, end, last, X0, X1, X2, X3)                          \
    {                                                                         \
        int e1 = (e) + 8, e2 = (e) + 16, e3 = (e) + 24;                       \
        int2 ra = REC8(basec, (e));                                           \
        int2 rb = REC8(basec, min(e1, last));                                 \
        int2 rc = REC8(basec, min(e2, last));                                 \
        int2 rd = REC8(basec, min(e3, last));                                 \
        rb.y = (e1 < (end)) ? rb.y : 0;                                       \
        rc.y = (e2 < (end)) ? rc.y : 0;                                       \
        rd.y = (e3 < (end)) ? rd.y : 0;                                       \
        uint4 ua = GATHER16(einc, ra);                                        \
        uint4 ub = GATHER16(einc, rb);                                        \
        uint4 uc = GATHER16(einc, rc);                                        \
        uint4 ud = GATHER16(einc, rd);                                        \
        EDGE_FMA(ra, ua, X0, X1, X2, X3);                                     \
        EDGE_FMA(rb, ub, X0, X1, X2, X3);                                     \
        EDGE_FMA(rc, uc, X0, X1, X2, X3);                                     \
        EDGE_FMA(rd, ud, X0, X1, X2, X3);                                     \
        (e) += 32;                                                            \
    }

__global__ void k_spmm16(const ushort* __restrict__ ein, ushort* __restrict__ eout,
                         const int* __restrict__ row_ptr, const int2* __restrict__ fin,
                         const int* __restrict__ users, const int* __restrict__ items,
                         unsigned int* __restrict__ bmw, const unsigned int* __restrict__ bmr,
                         int mark_blocks) {
    if (blockIdx.x < (unsigned)mark_blocks) {
        // marker branch (pass 1 only): one thread per sampled slot; bitmap is consumed
        // by the NEXT launch, so no intra-kernel ordering needed.
        int slot = blockIdx.x * 256 + threadIdx.x;
        if (slot >= 2 * BATCH) return;
        int node = (slot < BATCH) ? users[slot] : (items[slot - BATCH] + N_USERS);
        atomicOr(&bmw[node >> 5], 1u << (node & 31));
        int s0 = row_ptr[node], s1 = row_ptr[node + 1];
        for (int e = s0; e < s1; e++) {
            int s = fin[e].x;
            atomicOr(&bmw[s >> 5], 1u << (s & 31));
        }
        return;
    }
    int wave = ((blockIdx.x - mark_blocks) * 256 + (int)threadIdx.x) >> 6;
    if (wave >= N_NODES) return;
    if (bmr && !((bmr[wave >> 5] >> (wave & 31)) & 1u)) return;  // unmarked: dead row
    int lane = threadIdx.x & 63;
    int g = lane >> 3;  // edge group 0..7
    int q = lane & 7;   // 8 bf16 dims per lane
    unsigned int qoff = (unsigned int)q << 4;
    const char* einc = (const char*)ein;
    const char* finc = (const char*)fin;
    int start = row_ptr[wave], end = row_ptr[wave + 1];
    int last = max(start, end - 1);
    v2f A0 = {0.f, 0.f}, A1 = {0.f, 0.f}, A2 = {0.f, 0.f}, A3 = {0.f, 0.f};
    int e = start + g;
    while (e < end) BURST32(finc, e, end, last, A0, A1, A2, A3);
#pragma unroll
    for (int off = 8; off < 64; off <<= 1) {
        A0.x += __shfl_xor(A0.x, off);
        A0.y += __shfl_xor(A0.y, off);
        A1.x += __shfl_xor(A1.x, off);
        A1.y += __shfl_xor(A1.y, off);
        A2.x += __shfl_xor(A2.x, off);
        A2.y += __shfl_xor(A2.y, off);
        A3.x += __shfl_xor(A3.x, off);
        A3.y += __shfl_xor(A3.y, off);
    }
    if (lane < 8) {
        uint4 p;
        p.x = pack2(A0.x, A0.y);
        p.y = pack2(A1.x, A1.y);
        p.z = pack2(A2.x, A2.y);
        p.w = pack2(A3.x, A3.y);
        *(uint4*)(eout + (size_t)wave * DIM + q * 8) = p;
    }
}

// ---------------- fused sampled tail: layer-3 + layer accumulate + dot ----------------
__global__ void k_sampdot(const float* __restrict__ uemb, const float* __restrict__ iemb,
                          const ushort* __restrict__ ebf1, const ushort* __restrict__ ebf2,
                          const int* __restrict__ row_ptr, const int2* __restrict__ fin,
                          const int* __restrict__ users, const int* __restrict__ items,
                          float* __restrict__ out) {
    int b = (blockIdx.x * blockDim.x + threadIdx.x) >> 6;
    if (b >= BATCH) return;
    int lane = threadIdx.x & 63;
    int g = lane >> 3;
    int q = lane & 7;
    unsigned int qoff = (unsigned int)q << 4;
    const char* einc = (const char*)ebf2;  // layer-3 propagates from ebf2
    const char* finc = (const char*)fin;
    int iu = users[b];
    int ii = items[b];
    int nu = iu, ni = ii + N_USERS;
    // ---- user row ----
    v2f A0 = {0.f, 0.f}, A1 = {0.f, 0.f}, A2 = {0.f, 0.f}, A3 = {0.f, 0.f};
    {
        int start = row_ptr[nu], end = row_ptr[nu + 1];
        int last = max(start, end - 1);
        int e = start + g;
        while (e < end) BURST32(finc, e, end, last, A0, A1, A2, A3);
    }
    // ---- item row ----
    v2f B0 = {0.f, 0.f}, B1 = {0.f, 0.f}, B2 = {0.f, 0.f}, B3 = {0.f, 0.f};
    {
        int start = row_ptr[ni], end = row_ptr[ni + 1];
        int last = max(start, end - 1);
        int e = start + g;
        while (e < end) BURST32(finc, e, end, last, B0, B1, B2, B3);
    }
#pragma unroll
    for (int off = 8; off < 64; off <<= 1) {
        A0.x += __shfl_xor(A0.x, off);
        A0.y += __shfl_xor(A0.y, off);
        A1.x += __shfl_xor(A1.x, off);
        A1.y += __shfl_xor(A1.y, off);
        A2.x += __shfl_xor(A2.x, off);
        A2.y += __shfl_xor(A2.y, off);
        A3.x += __shfl_xor(A3.x, off);
        A3.y += __shfl_xor(A3.y, off);
        B0.x += __shfl_xor(B0.x, off);
        B0.y += __shfl_xor(B0.y, off);
        B1.x += __shfl_xor(B1.x, off);
        B1.y += __shfl_xor(B1.y, off);
        B2.x += __shfl_xor(B2.x, off);
        B2.y += __shfl_xor(B2.y, off);
        B3.x += __shfl_xor(B3.x, off);
        B3.y += __shfl_xor(B3.y, off);
    }
    // layers 0..2: fp32 table row + ebf1 row + ebf2 row (each lane: dims q*8..q*8+7)
    {
        const float4* fp = (const float4*)(uemb + (size_t)nu * DIM + q * 8);
        float4 fa = fp[0], fb = fp[1];
        uint4 u1 = *(const uint4*)(ebf1 + (size_t)nu * DIM + q * 8);
        uint4 u2 = *(const uint4*)(ebf2 + (size_t)nu * DIM + q * 8);
        A0.x += fa.x + blo(u1.x) + blo(u2.x); A0.y += fa.y + bhi(u1.x) + bhi(u2.x);
        A1.x += fa.z + blo(u1.y) + blo(u2.y); A1.y += fa.w + bhi(u1.y) + bhi(u2.y);
        A2.x += fb.x + blo(u1.z) + blo(u2.z); A2.y += fb.y + bhi(u1.z) + bhi(u2.z);
        A3.x += fb.z + blo(u1.w) + blo(u2.w); A3.y += fb.w + bhi(u1.w) + bhi(u2.w);
    }
    {
        const float4* fp = (const float4*)(iemb + (size_t)ii * DIM + q * 8);
        float4 fa = fp[0], fb = fp[1];
        uint4 u1 = *(const uint4*)(ebf1 + (size_t)ni * DIM + q * 8);
        uint4 u2 = *(const uint4*)(ebf2 + (size_t)ni * DIM + q * 8);
        B0.x += fa.x + blo(u1.x) + blo(u2.x); B0.y += fa.y + bhi(u1.x) + bhi(u2.x);
        B1.x += fa.z + blo(u1.y) + blo(u2.y); B1.y += fa.w + bhi(u1.y) + bhi(u2.y);
        B2.x += fb.x + blo(u1.z) + blo(u2.z); B2.y += fb.y + bhi(u1.z) + bhi(u2.z);
        B3.x += fb.z + blo(u1.w) + blo(u2.w); B3.y += fb.w + bhi(u1.w) + bhi(u2.w);
    }
    // dot: per-lane 8-dim product, reduce across q (lanes 0..7 cover all 64 dims)
    float p = A0.x * B0.x + A0.y * B0.y + A1.x * B1.x + A1.y * B1.y +
              A2.x * B2.x + A2.y * B2.y + A3.x * B3.x + A3.y * B3.y;
    p += __shfl_xor(p, 1);
    p += __shfl_xor(p, 2);
    p += __shfl_xor(p, 4);
    if (lane == 0) out[b] = p * (1.0f / 16.0f);  // (acc/4)·(acc/4)
}

// ---------------- launch ----------------

extern "C" void kernel_launch(void* const* d_in, const int* in_sizes, int n_in,
                              void* d_out, int out_size, void* d_ws, size_t ws_size,
                              hipStream_t stream) {
    const float* user_emb = (const float*)d_in[0];
    const float* item_emb = (const float*)d_in[1];
    const float* vals = (const float*)d_in[2];
    const int* src = (const int*)d_in[3];
    const int* dst = (const int*)d_in[4];
    const int* users = (const int*)d_in[5];
    const int* items = (const int*)d_in[6];
    float* out = (float*)d_out;

    char* ws = (char*)d_ws;
    size_t off = 0;
    auto alloc = [&](size_t bytes) {
        char* p = ws + off;
        off += (bytes + 255) & ~(size_t)255;
        return p;
    };
    ushort* ebf0 = (ushort*)alloc((size_t)N_NODES * DIM * 2);  // 19.2 MB bf16 concat tables
    ushort* ebf1 = (ushort*)alloc((size_t)N_NODES * DIM * 2);  // layer-1 out (aliases tmp lo)
    ushort* ebf2 = (ushort*)alloc((size_t)N_NODES * DIM * 2);  // layer-2 out (aliases tmp hi)
    int2* fin = (int2*)alloc((size_t)N_EDGES * 8);             // 32 MB dense CSR records
    int* row_ptr = (int*)alloc((size_t)(N_NODES + 1) * 4);
    int* gcur = (int*)alloc((size_t)NBKT * 4);
    unsigned int* bitmap = (unsigned int*)alloc((size_t)BMAP_WORDS * 4);  // marked-node bits
    // 34.1 MB fixed-stride partition scratch aliases ebf1+ebf2 (38.4 MB contiguous);
    // tmp is dead after k_bsortcvt, before ebf1/2 are first written.
    int2* tmp = (int2*)ebf1;

    (void)hipMemsetAsync(gcur, 0, (size_t)NBKT * 4, stream);
    (void)hipMemsetAsync(bitmap, 0, (size_t)BMAP_WORDS * 4, stream);

    // pure partition (977 blocks)
    k_partition<<<PA_BLOCKS, 256, 0, stream>>>(src, dst, vals, gcur, tmp);
    // bucket sort (256 blocks, 133 KB dyn LDS) + grid-stride table convert
    k_bsortcvt<<<NBKT + CVT_BLOCKS, 512, (size_t)STRIDE * 8, stream>>>(
        tmp, gcur, row_ptr, fin, user_emb, item_emb, ebf0);

    // layer 1 (full) + front-loaded bitmap build: ebf0 -> ebf1
    k_spmm16<<<MARK_BLOCKS + SPMM_BLOCKS, 256, 0, stream>>>(
        ebf0, ebf1, row_ptr, fin, users, items, bitmap, nullptr, MARK_BLOCKS);
    // layer 2 (marked rows only, ~77%): ebf1 -> ebf2
    k_spmm16<<<SPMM_BLOCKS, 256, 0, stream>>>(
        ebf1, ebf2, row_ptr, fin, users, items, nullptr, bitmap, 0);
    // fused sampled tail: layer-3 + layer-0/1/2 accumulate + dot
    k_sampdot<<<(BATCH * 64 + 255) / 256, 256, 0, stream>>>(
        user_emb, item_emb, ebf1, ebf2, row_ptr, fin, users, items, out);
}